// Round 10
// baseline (372.782 us; speedup 1.0000x reference)
//
#include <hip/hip_runtime.h>
#include <hip/hip_bf16.h>

#define LEAKY 0.2f
#define BINB 8          // 256 nodes per bin (requires N <= 65536 for u16 packing)
#define TILE 2048       // edges per block in binning kernels
#define CAP 8192        // LDS bucket-segment capacity per bin (avg ~4081)
#define NPB 128         // nodes per block in aggregate (4 waves x 32)
#define NPW 32

static inline int ceil_div(int a, int b) { return (a + b - 1) / b; }

typedef __bf16 bf16x8 __attribute__((ext_vector_type(8)));
typedef float f32x4 __attribute__((ext_vector_type(4)));

// f32 -> bf16 bits, round-to-nearest-even
__device__ __forceinline__ ushort f2bf(float f) {
    unsigned int x = __float_as_uint(f);
    unsigned int r = (x + 0x7fffu + ((x >> 16) & 1u)) >> 16;
    return (ushort)r;
}
__device__ __forceinline__ float bflo(unsigned int u) { return __uint_as_float(u << 16); }
__device__ __forceinline__ float bfhi(unsigned int u) { return __uint_as_float(u & 0xffff0000u); }

// ---------------- CSR build (two-level, coalesced writes) ----------------
// Round-4 lesson: one-pass random 4B scatter = 17x HBM write amplification.

__global__ __launch_bounds__(256) void bin_count(const int* __restrict__ dst,
                                                 int* __restrict__ bin_cnt, int E, int NB) {
    __shared__ int h[256];
    int t = threadIdx.x;
    h[t] = 0;
    __syncthreads();
    int base = blockIdx.x * TILE;
#pragma unroll
    for (int j = 0; j < TILE / 256; ++j) {
        int i = base + j * 256 + t;
        if (i < E) atomicAdd(&h[dst[i] >> BINB], 1);
    }
    __syncthreads();
    if (t < NB && h[t]) atomicAdd(&bin_cnt[t], h[t]);
}

__global__ __launch_bounds__(256) void bin_scan(const int* __restrict__ bin_cnt,
                                                int* __restrict__ binStart,
                                                int* __restrict__ bin_cursor,
                                                int* __restrict__ rowstart,
                                                int NB, int N, int E) {
    __shared__ int s[256];
    int t = threadIdx.x;
    int v = (t < NB) ? bin_cnt[t] : 0;
    s[t] = v;
    __syncthreads();
    for (int off = 1; off < 256; off <<= 1) {
        int x = (t >= off) ? s[t - off] : 0;
        __syncthreads();
        s[t] += x;
        __syncthreads();
    }
    int excl = s[t] - v;
    if (t < NB) {
        binStart[t] = excl;
        bin_cursor[t] = excl;
        if (t == NB - 1) binStart[NB] = excl + v;
    }
    if (t == 0) rowstart[N] = E;
}

__global__ __launch_bounds__(256) void bin_scatter(const int* __restrict__ src,
                                                   const int* __restrict__ dst,
                                                   int* __restrict__ bin_cursor,
                                                   unsigned int* __restrict__ coarse, int E) {
    __shared__ int hist[256], scn[256], gbase[256], lcur[256];
    __shared__ unsigned int outp[TILE];
    __shared__ int gidx[TILE];
    int t = threadIdx.x;
    hist[t] = 0;
    __syncthreads();
    int base = blockIdx.x * TILE;
    int dloc[TILE / 256];
#pragma unroll
    for (int j = 0; j < TILE / 256; ++j) {
        int i = base + j * 256 + t;
        int d = (i < E) ? dst[i] : -1;
        dloc[j] = d;
        if (d >= 0) atomicAdd(&hist[d >> BINB], 1);
    }
    __syncthreads();
    int hv = hist[t];
    scn[t] = hv;
    __syncthreads();
    for (int off = 1; off < 256; off <<= 1) {
        int x = (t >= off) ? scn[t - off] : 0;
        __syncthreads();
        scn[t] += x;
        __syncthreads();
    }
    int excl = scn[t] - hv;
    if (hv > 0) gbase[t] = atomicAdd(&bin_cursor[t], hv);
    lcur[t] = excl;
    scn[t] = excl;
    __syncthreads();
#pragma unroll
    for (int j = 0; j < TILE / 256; ++j) {
        int i = base + j * 256 + t;
        int d = dloc[j];
        if (d >= 0) {
            int b = d >> BINB;
            int pos = atomicAdd(&lcur[b], 1);
            outp[pos] = (unsigned int)src[i] | ((unsigned int)(d & ((1 << BINB) - 1)) << 16);
            gidx[pos] = gbase[b] + (pos - scn[b]);
        }
    }
    __syncthreads();
    int cnt = min(TILE, E - base);
    for (int j = t; j < cnt; j += 256) coarse[gidx[j]] = outp[j];
}

__global__ __launch_bounds__(256) void fine_csr(const unsigned int* __restrict__ coarse,
                                                const int* __restrict__ binStart,
                                                int* __restrict__ rowstart,
                                                ushort* __restrict__ bucket, int N) {
    __shared__ int hist[256], scn[256], cur[256];
    __shared__ ushort sb[CAP];
    int b = blockIdx.x, t = threadIdx.x;
    int e0 = binStart[b], e1 = binStart[b + 1];
    int cnt = e1 - e0;
    hist[t] = 0;
    __syncthreads();
    for (int j = e0 + t; j < e1; j += 256) atomicAdd(&hist[coarse[j] >> 16], 1);
    __syncthreads();
    int hv = hist[t];
    scn[t] = hv;
    __syncthreads();
    for (int off = 1; off < 256; off <<= 1) {
        int x = (t >= off) ? scn[t - off] : 0;
        __syncthreads();
        scn[t] += x;
        __syncthreads();
    }
    int excl = scn[t] - hv;
    int n = (b << BINB) + t;
    if (n < N) rowstart[n] = e0 + excl;
    cur[t] = excl;
    __syncthreads();
    bool fit = (cnt <= CAP);
    for (int j = e0 + t; j < e1; j += 256) {
        unsigned int p = coarse[j];
        int dl = p >> 16;
        int pos = atomicAdd(&cur[dl], 1);
        ushort sv = (ushort)(p & 0xffffu);
        if (fit) sb[pos] = sv;
        else bucket[e0 + pos] = sv;
    }
    __syncthreads();
    if (fit)
        for (int j = t; j < cnt; j += 256) bucket[e0 + j] = sb[j];
}

// ---------------- W convert: Wt[n][k] = bf16(W[k][n]) ----------------
__global__ __launch_bounds__(256) void convert_w(const float* __restrict__ W1,
                                                 const float* __restrict__ W2,
                                                 ushort* __restrict__ Wt1,
                                                 ushort* __restrict__ Wt2) {
    int idx = blockIdx.x * 256 + threadIdx.x;
    const float* W = (idx < 16384) ? W1 : W2;
    ushort* O = (idx < 16384) ? Wt1 : Wt2;
    int i = idx & 16383;
    int k = i >> 7, n = i & 127;
    O[n * 128 + k] = f2bf(W[i]);
}

// ---------------- MFMA GEMM + attention coefficients ----------------
// Block 64x128, 4 waves (2M x 2N). Outputs in HEAD-SLICED layouts:
//   feat [8][N][16] bf16, el/er [8][N] f32  (enables XCD-local aggregation).
// Layer-2 input is h1 in the same sliced layout (BF16IN path).
#define LDK 136
template <bool BF16IN>
__global__ __launch_bounds__(256) void gemm_attn_mfma(const void* __restrict__ in_,
                                                      const ushort* __restrict__ Wt,
                                                      const float* __restrict__ al,
                                                      const float* __restrict__ ar,
                                                      ushort* __restrict__ feat,
                                                      float* __restrict__ el,
                                                      float* __restrict__ er, int N) {
    __shared__ ushort sA[64 * LDK];
    int tid = threadIdx.x;
    int rowbase = blockIdx.x * 64;

    if (BF16IN) {
        const ushort* in = (const ushort*)in_;  // sliced [8][N][16]
#pragma unroll
        for (int i = 0; i < 4; ++i) {
            int idx8 = i * 256 + tid;
            int flat = idx8 * 8;
            int row = flat >> 7, col = flat & 127;   // col%16 in {0,8}
            int grow = rowbase + row;
            int hh = col >> 4, d = col & 15;
            uint4 v = make_uint4(0, 0, 0, 0);
            if (grow < N)
                v = *reinterpret_cast<const uint4*>(in + ((size_t)hh * N + grow) * 16 + d);
            *reinterpret_cast<uint4*>(&sA[row * LDK + col]) = v;
        }
    } else {
        const float* in = (const float*)in_;
#pragma unroll
        for (int i = 0; i < 8; ++i) {
            int idx4 = i * 256 + tid;
            int flat = idx4 * 4;
            int row = flat >> 7, col = flat & 127;
            int grow = rowbase + row;
            float4 v = make_float4(0.f, 0.f, 0.f, 0.f);
            if (grow < N) v = *reinterpret_cast<const float4*>(in + (size_t)grow * 128 + col);
            uint2 w;
            w.x = (unsigned int)f2bf(v.x) | ((unsigned int)f2bf(v.y) << 16);
            w.y = (unsigned int)f2bf(v.z) | ((unsigned int)f2bf(v.w) << 16);
            *reinterpret_cast<uint2*>(&sA[row * LDK + col]) = w;
        }
    }
    __syncthreads();

    int wid = tid >> 6;
    int lane = tid & 63;
    int wm = wid >> 1;
    int wn = wid & 1;
    int l15 = lane & 15;
    int lhi = lane >> 4;

    f32x4 acc[2][4] = {};
    const ushort* wb = Wt + (size_t)(wn * 64 + l15) * 128 + lhi * 8;
    const ushort* a0p = &sA[(wm * 32 + l15) * LDK + lhi * 8];
    const ushort* a1p = &sA[(wm * 32 + 16 + l15) * LDK + lhi * 8];

#pragma unroll
    for (int ks = 0; ks < 4; ++ks) {
        bf16x8 a0 = *reinterpret_cast<const bf16x8*>(a0p + ks * 32);
        bf16x8 a1 = *reinterpret_cast<const bf16x8*>(a1p + ks * 32);
#pragma unroll
        for (int ni = 0; ni < 4; ++ni) {
            bf16x8 b = *reinterpret_cast<const bf16x8*>(wb + ni * 16 * 128 + ks * 32);
            acc[0][ni] = __builtin_amdgcn_mfma_f32_16x16x32_bf16(a0, b, acc[0][ni], 0, 0, 0);
            acc[1][ni] = __builtin_amdgcn_mfma_f32_16x16x32_bf16(a1, b, acc[1][ni], 0, 0, 0);
        }
    }

#pragma unroll
    for (int ni = 0; ni < 4; ++ni) {
        int head = wn * 4 + ni;
        float alv = al[head * 16 + l15];
        float arv = ar[head * 16 + l15];
#pragma unroll
        for (int mi = 0; mi < 2; ++mi) {
#pragma unroll
            for (int reg = 0; reg < 4; ++reg) {
                int row = rowbase + wm * 32 + mi * 16 + lhi * 4 + reg;
                float v = acc[mi][ni][reg];
                float pl = v * alv;
                float pr = v * arv;
#pragma unroll
                for (int off = 8; off; off >>= 1) {
                    pl += __shfl_xor(pl, off);
                    pr += __shfl_xor(pr, off);
                }
                if (row < N) {
                    feat[((size_t)head * N + row) * 16 + l15] = f2bf(v);
                    if (l15 == 0) {
                        el[(size_t)head * N + row] = pl;
                        er[(size_t)head * N + row] = pr;
                    }
                }
            }
        }
    }
}

// ---------------- per-dst-node softmax + aggregation (head-sliced, XCD-affine) ----
// head = blockIdx % 8 -> all blocks for head h land on XCD h (round-robin idiom);
// XCD h's L2 only sees feat slice h (1.6MB) + el slice (200KB): fully resident,
// killing the 8x whole-table HBM re-fetch (round-8 FETCH was 102MB = 8 x 12.8MB).
// Wave = 16 edges x 4 lanes (uint2 = 4 dims/lane). p is computed in the lanes that
// consume it: no LDS, no bpermute in the main loop, one exp instr per 16 edges.
__global__ __launch_bounds__(256) void aggregate(const ushort* __restrict__ feat_s, // [8][N][16]
                                                 const float* __restrict__ el_t,    // [8][N]
                                                 const float* __restrict__ er_t,    // [8][N]
                                                 const int* __restrict__ rowstart,
                                                 const ushort* __restrict__ bucket,
                                                 const float* __restrict__ bias,    // [8][16]
                                                 ushort* __restrict__ out_s,        // [8][N][16]
                                                 int N, int do_relu) {
    int h = blockIdx.x & 7;
    int g = blockIdx.x >> 3;
    int w = threadIdx.x >> 6;
    int lane = threadIdx.x & 63;
    int eg = lane >> 2;  // edge slot 0..15
    int dl = lane & 3;   // dim quarter 0..3

    const float* elh = el_t + (size_t)h * N;
    const float* erh = er_t + (size_t)h * N;
    const uint2* fs = reinterpret_cast<const uint2*>(feat_s) + (size_t)h * N * 4 + dl;
    uint2* os = reinterpret_cast<uint2*>(out_s) + (size_t)h * N * 4;
    float4 bv = *reinterpret_cast<const float4*>(bias + h * 16 + dl * 4);

    int n0 = g * NPB + w * NPW;
    int n1 = min(n0 + NPW, N);

    for (int n = n0; n < n1; ++n) {
        int beg = rowstart[n];
        int end = rowstart[n + 1];
        float erv = erh[n];
        float ax = 0.f, ay = 0.f, az = 0.f, aw = 0.f, lsum = 0.f;

        for (int base = beg; base < end; base += 16) {
            int j = base + eg;
            bool vld = j < end;
            int s = (int)bucket[vld ? j : beg];  // 32B contiguous, 4-lane broadcast
            float e = elh[s] + erv;              // 4B broadcast gather (L2-resident slice)
            e = (e > 0.0f) ? e : LEAKY * e;
            float p = vld ? __expf(e) : 0.0f;    // one exp instr covers 16 edges
            lsum += p;
            uint2 u = fs[(size_t)s * 4];         // 32B/edge contiguous over 4 lanes
            ax = fmaf(p, bflo(u.x), ax);
            ay = fmaf(p, bfhi(u.x), ay);
            az = fmaf(p, bflo(u.y), az);
            aw = fmaf(p, bfhi(u.y), aw);
        }

        // reduce the 16 edge-groups (lanes sharing dl): masks 4,8,16,32
#pragma unroll
        for (int m = 4; m <= 32; m <<= 1) {
            ax += __shfl_xor(ax, m);
            ay += __shfl_xor(ay, m);
            az += __shfl_xor(az, m);
            aw += __shfl_xor(aw, m);
            lsum += __shfl_xor(lsum, m);
        }
        float inv = (end > beg) ? 1.0f / lsum : 0.0f;
        float o0 = fmaf(ax, inv, bv.x);
        float o1 = fmaf(ay, inv, bv.y);
        float o2 = fmaf(az, inv, bv.z);
        float o3 = fmaf(aw, inv, bv.w);
        if (do_relu) {
            o0 = fmaxf(o0, 0.f); o1 = fmaxf(o1, 0.f);
            o2 = fmaxf(o2, 0.f); o3 = fmaxf(o3, 0.f);
        }
        if (lane < 4) {  // dl == lane
            uint2 pk;
            pk.x = (unsigned int)f2bf(o0) | ((unsigned int)f2bf(o1) << 16);
            pk.y = (unsigned int)f2bf(o2) | ((unsigned int)f2bf(o3) << 16);
            os[(size_t)n * 4 + lane] = pk;
        }
    }
}

// ---------------- readout (h2 in sliced layout) ----------------
__global__ __launch_bounds__(256) void mean_reduce(const ushort* __restrict__ h,
                                                   float* __restrict__ meanbuf, int N) {
    int c = threadIdx.x & 127;
    int hh = c >> 4, d = c & 15;
    int rbase = blockIdx.x * 2 + (threadIdx.x >> 7);
    float s = 0.0f;
    for (int r = rbase; r < N; r += gridDim.x * 2)
        s += __uint_as_float((unsigned int)h[((size_t)hh * N + r) * 16 + d] << 16);
    atomicAdd(&meanbuf[c], s);
}

__global__ __launch_bounds__(64) void classifier(const float* __restrict__ meanbuf,
                                                 const float* __restrict__ Wc,
                                                 const float* __restrict__ bc,
                                                 float* __restrict__ outp, float invN) {
    int j = threadIdx.x;
    if (j < 10) {
        float s = 0.0f;
        for (int k = 0; k < 128; ++k) s += meanbuf[k] * invN * Wc[k * 10 + j];
        outp[j] = s + bc[j];
    }
}

// ---------------- launch ----------------

extern "C" void kernel_launch(void* const* d_in, const int* in_sizes, int n_in,
                              void* d_out, int out_size, void* d_ws, size_t ws_size,
                              hipStream_t stream) {
    const float* x   = (const float*)d_in[0];
    const int*   src = (const int*)d_in[1];
    const int*   dst = (const int*)d_in[2];
    const float* W1  = (const float*)d_in[3];
    const float* al1 = (const float*)d_in[4];
    const float* ar1 = (const float*)d_in[5];
    const float* b1  = (const float*)d_in[6];
    const float* W2  = (const float*)d_in[7];
    const float* al2 = (const float*)d_in[8];
    const float* ar2 = (const float*)d_in[9];
    const float* b2  = (const float*)d_in[10];
    const float* Wc  = (const float*)d_in[11];
    const float* bc  = (const float*)d_in[12];

    int N = in_sizes[0] / 128;
    int E = in_sizes[1];
    int NB = (N + (1 << BINB) - 1) >> BINB;

    size_t off = 0;
    auto alloc = [&](size_t bytes) -> void* {
        void* p = (char*)d_ws + off;
        off += (bytes + 255) & ~size_t(255);
        return p;
    };
    int*   bin_cnt    = (int*)alloc(sizeof(int) * NB);
    int*   binStart   = (int*)alloc(sizeof(int) * (NB + 1));
    int*   bin_cursor = (int*)alloc(sizeof(int) * NB);
    int*   rowstart   = (int*)alloc(sizeof(int) * (N + 1));
    unsigned int* coarse = (unsigned int*)alloc(sizeof(unsigned int) * E);
    ushort* bucket  = (ushort*)alloc(sizeof(ushort) * E);
    ushort* feat    = (ushort*)alloc(sizeof(ushort) * (size_t)N * 128);
    float* el       = (float*)alloc(sizeof(float) * N * 8);
    float* er       = (float*)alloc(sizeof(float) * N * 8);
    ushort* h1      = (ushort*)alloc(sizeof(ushort) * (size_t)N * 128);
    ushort* h2      = (ushort*)alloc(sizeof(ushort) * (size_t)N * 128);
    float* meanbuf  = (float*)alloc(sizeof(float) * 128);
    ushort* Wt1     = (ushort*)alloc(sizeof(ushort) * 128 * 128);
    ushort* Wt2     = (ushort*)alloc(sizeof(ushort) * 128 * 128);

    hipMemsetAsync(bin_cnt, 0, sizeof(int) * NB, stream);
    hipMemsetAsync(meanbuf, 0, sizeof(float) * 128, stream);

    int GB = ceil_div(E, TILE);
    int AGG = ceil_div(N, NPB) * 8;  // nodegroups x 8 heads, head = blockIdx%8

    bin_count<<<GB, 256, 0, stream>>>(dst, bin_cnt, E, NB);
    bin_scan<<<1, 256, 0, stream>>>(bin_cnt, binStart, bin_cursor, rowstart, NB, N, E);
    bin_scatter<<<GB, 256, 0, stream>>>(src, dst, bin_cursor, coarse, E);
    fine_csr<<<NB, 256, 0, stream>>>(coarse, binStart, rowstart, bucket, N);
    convert_w<<<128, 256, 0, stream>>>(W1, W2, Wt1, Wt2);

    // layer 1 (f32 input)
    gemm_attn_mfma<false><<<ceil_div(N, 64), 256, 0, stream>>>(x, Wt1, al1, ar1, feat, el, er, N);
    aggregate<<<AGG, 256, 0, stream>>>(feat, el, er, rowstart, bucket, b1, h1, N, 1);
    // layer 2 (sliced bf16 input)
    gemm_attn_mfma<true><<<ceil_div(N, 64), 256, 0, stream>>>(h1, Wt2, al2, ar2, feat, el, er, N);
    aggregate<<<AGG, 256, 0, stream>>>(feat, el, er, rowstart, bucket, b2, h2, N, 0);
    // readout
    mean_reduce<<<256, 256, 0, stream>>>(h2, meanbuf, N);
    classifier<<<1, 64, 0, stream>>>(meanbuf, Wc, bc, (float*)d_out, 1.0f / (float)N);
}

// Round 11
// 299.364 us; speedup vs baseline: 1.2452x; 1.2452x over previous
//
#include <hip/hip_runtime.h>
#include <hip/hip_bf16.h>

#define LEAKY 0.2f
#define BINB 8          // 256 nodes per bin (requires N <= 65536 for u16 packing)
#define TILE 2048       // edges per block in binning kernels
#define CAP 8192        // LDS bucket-segment capacity per bin (avg ~4081)

static inline int ceil_div(int a, int b) { return (a + b - 1) / b; }

typedef __bf16 bf16x8 __attribute__((ext_vector_type(8)));
typedef float f32x4 __attribute__((ext_vector_type(4)));

// f32 -> bf16 bits, round-to-nearest-even
__device__ __forceinline__ ushort f2bf(float f) {
    unsigned int x = __float_as_uint(f);
    unsigned int r = (x + 0x7fffu + ((x >> 16) & 1u)) >> 16;
    return (ushort)r;
}
__device__ __forceinline__ float bflo(unsigned int u) { return __uint_as_float(u << 16); }
__device__ __forceinline__ float bfhi(unsigned int u) { return __uint_as_float(u & 0xffff0000u); }

// ---------------- CSR build (two-level, coalesced writes) ----------------
// Round-4 lesson: one-pass random 4B scatter = 17x HBM write amplification.

__global__ __launch_bounds__(256) void bin_count(const int* __restrict__ dst,
                                                 int* __restrict__ bin_cnt, int E, int NB) {
    __shared__ int h[256];
    int t = threadIdx.x;
    h[t] = 0;
    __syncthreads();
    int base = blockIdx.x * TILE;
#pragma unroll
    for (int j = 0; j < TILE / 256; ++j) {
        int i = base + j * 256 + t;
        if (i < E) atomicAdd(&h[dst[i] >> BINB], 1);
    }
    __syncthreads();
    if (t < NB && h[t]) atomicAdd(&bin_cnt[t], h[t]);
}

__global__ __launch_bounds__(256) void bin_scan(const int* __restrict__ bin_cnt,
                                                int* __restrict__ binStart,
                                                int* __restrict__ bin_cursor,
                                                int* __restrict__ rowstart,
                                                int NB, int N, int E) {
    __shared__ int s[256];
    int t = threadIdx.x;
    int v = (t < NB) ? bin_cnt[t] : 0;
    s[t] = v;
    __syncthreads();
    for (int off = 1; off < 256; off <<= 1) {
        int x = (t >= off) ? s[t - off] : 0;
        __syncthreads();
        s[t] += x;
        __syncthreads();
    }
    int excl = s[t] - v;
    if (t < NB) {
        binStart[t] = excl;
        bin_cursor[t] = excl;
        if (t == NB - 1) binStart[NB] = excl + v;
    }
    if (t == 0) rowstart[N] = E;
}

__global__ __launch_bounds__(256) void bin_scatter(const int* __restrict__ src,
                                                   const int* __restrict__ dst,
                                                   int* __restrict__ bin_cursor,
                                                   unsigned int* __restrict__ coarse, int E) {
    __shared__ int hist[256], scn[256], gbase[256], lcur[256];
    __shared__ unsigned int outp[TILE];
    __shared__ int gidx[TILE];
    int t = threadIdx.x;
    hist[t] = 0;
    __syncthreads();
    int base = blockIdx.x * TILE;
    int dloc[TILE / 256];
#pragma unroll
    for (int j = 0; j < TILE / 256; ++j) {
        int i = base + j * 256 + t;
        int d = (i < E) ? dst[i] : -1;
        dloc[j] = d;
        if (d >= 0) atomicAdd(&hist[d >> BINB], 1);
    }
    __syncthreads();
    int hv = hist[t];
    scn[t] = hv;
    __syncthreads();
    for (int off = 1; off < 256; off <<= 1) {
        int x = (t >= off) ? scn[t - off] : 0;
        __syncthreads();
        scn[t] += x;
        __syncthreads();
    }
    int excl = scn[t] - hv;
    if (hv > 0) gbase[t] = atomicAdd(&bin_cursor[t], hv);
    lcur[t] = excl;
    scn[t] = excl;
    __syncthreads();
#pragma unroll
    for (int j = 0; j < TILE / 256; ++j) {
        int i = base + j * 256 + t;
        int d = dloc[j];
        if (d >= 0) {
            int b = d >> BINB;
            int pos = atomicAdd(&lcur[b], 1);
            outp[pos] = (unsigned int)src[i] | ((unsigned int)(d & ((1 << BINB) - 1)) << 16);
            gidx[pos] = gbase[b] + (pos - scn[b]);
        }
    }
    __syncthreads();
    int cnt = min(TILE, E - base);
    for (int j = t; j < cnt; j += 256) coarse[gidx[j]] = outp[j];
}

__global__ __launch_bounds__(256) void fine_csr(const unsigned int* __restrict__ coarse,
                                                const int* __restrict__ binStart,
                                                int* __restrict__ rowstart,
                                                ushort* __restrict__ bucket, int N) {
    __shared__ int hist[256], scn[256], cur[256];
    __shared__ ushort sb[CAP];
    int b = blockIdx.x, t = threadIdx.x;
    int e0 = binStart[b], e1 = binStart[b + 1];
    int cnt = e1 - e0;
    hist[t] = 0;
    __syncthreads();
    for (int j = e0 + t; j < e1; j += 256) atomicAdd(&hist[coarse[j] >> 16], 1);
    __syncthreads();
    int hv = hist[t];
    scn[t] = hv;
    __syncthreads();
    for (int off = 1; off < 256; off <<= 1) {
        int x = (t >= off) ? scn[t - off] : 0;
        __syncthreads();
        scn[t] += x;
        __syncthreads();
    }
    int excl = scn[t] - hv;
    int n = (b << BINB) + t;
    if (n < N) rowstart[n] = e0 + excl;
    cur[t] = excl;
    __syncthreads();
    bool fit = (cnt <= CAP);
    for (int j = e0 + t; j < e1; j += 256) {
        unsigned int p = coarse[j];
        int dl = p >> 16;
        int pos = atomicAdd(&cur[dl], 1);
        ushort sv = (ushort)(p & 0xffffu);
        if (fit) sb[pos] = sv;
        else bucket[e0 + pos] = sv;
    }
    __syncthreads();
    if (fit)
        for (int j = t; j < cnt; j += 256) bucket[e0 + j] = sb[j];
}

// ---------------- W convert: Wt[n][k] = bf16(W[k][n]) ----------------
__global__ __launch_bounds__(256) void convert_w(const float* __restrict__ W1,
                                                 const float* __restrict__ W2,
                                                 ushort* __restrict__ Wt1,
                                                 ushort* __restrict__ Wt2) {
    int idx = blockIdx.x * 256 + threadIdx.x;
    const float* W = (idx < 16384) ? W1 : W2;
    ushort* O = (idx < 16384) ? Wt1 : Wt2;
    int i = idx & 16383;
    int k = i >> 7, n = i & 127;
    O[n * 128 + k] = f2bf(W[i]);
}

// ---------------- MFMA GEMM + attention coefficients ----------------
// Block 64x128, 4 waves (2M x 2N). Outputs in HEAD-SLICED layouts:
//   feat [8][N][16] bf16, el/er [8][N] f32  (enables XCD-local aggregation).
// Layer-2 input is h1 in the same sliced layout (BF16IN path).
#define LDK 136
template <bool BF16IN>
__global__ __launch_bounds__(256) void gemm_attn_mfma(const void* __restrict__ in_,
                                                      const ushort* __restrict__ Wt,
                                                      const float* __restrict__ al,
                                                      const float* __restrict__ ar,
                                                      ushort* __restrict__ feat,
                                                      float* __restrict__ el,
                                                      float* __restrict__ er, int N) {
    __shared__ ushort sA[64 * LDK];
    int tid = threadIdx.x;
    int rowbase = blockIdx.x * 64;

    if (BF16IN) {
        const ushort* in = (const ushort*)in_;  // sliced [8][N][16]
#pragma unroll
        for (int i = 0; i < 4; ++i) {
            int idx8 = i * 256 + tid;
            int flat = idx8 * 8;
            int row = flat >> 7, col = flat & 127;   // col%16 in {0,8}
            int grow = rowbase + row;
            int hh = col >> 4, d = col & 15;
            uint4 v = make_uint4(0, 0, 0, 0);
            if (grow < N)
                v = *reinterpret_cast<const uint4*>(in + ((size_t)hh * N + grow) * 16 + d);
            *reinterpret_cast<uint4*>(&sA[row * LDK + col]) = v;
        }
    } else {
        const float* in = (const float*)in_;
#pragma unroll
        for (int i = 0; i < 8; ++i) {
            int idx4 = i * 256 + tid;
            int flat = idx4 * 4;
            int row = flat >> 7, col = flat & 127;
            int grow = rowbase + row;
            float4 v = make_float4(0.f, 0.f, 0.f, 0.f);
            if (grow < N) v = *reinterpret_cast<const float4*>(in + (size_t)grow * 128 + col);
            uint2 w;
            w.x = (unsigned int)f2bf(v.x) | ((unsigned int)f2bf(v.y) << 16);
            w.y = (unsigned int)f2bf(v.z) | ((unsigned int)f2bf(v.w) << 16);
            *reinterpret_cast<uint2*>(&sA[row * LDK + col]) = w;
        }
    }
    __syncthreads();

    int wid = tid >> 6;
    int lane = tid & 63;
    int wm = wid >> 1;
    int wn = wid & 1;
    int l15 = lane & 15;
    int lhi = lane >> 4;

    f32x4 acc[2][4] = {};
    const ushort* wb = Wt + (size_t)(wn * 64 + l15) * 128 + lhi * 8;
    const ushort* a0p = &sA[(wm * 32 + l15) * LDK + lhi * 8];
    const ushort* a1p = &sA[(wm * 32 + 16 + l15) * LDK + lhi * 8];

#pragma unroll
    for (int ks = 0; ks < 4; ++ks) {
        bf16x8 a0 = *reinterpret_cast<const bf16x8*>(a0p + ks * 32);
        bf16x8 a1 = *reinterpret_cast<const bf16x8*>(a1p + ks * 32);
#pragma unroll
        for (int ni = 0; ni < 4; ++ni) {
            bf16x8 b = *reinterpret_cast<const bf16x8*>(wb + ni * 16 * 128 + ks * 32);
            acc[0][ni] = __builtin_amdgcn_mfma_f32_16x16x32_bf16(a0, b, acc[0][ni], 0, 0, 0);
            acc[1][ni] = __builtin_amdgcn_mfma_f32_16x16x32_bf16(a1, b, acc[1][ni], 0, 0, 0);
        }
    }

#pragma unroll
    for (int ni = 0; ni < 4; ++ni) {
        int head = wn * 4 + ni;
        float alv = al[head * 16 + l15];
        float arv = ar[head * 16 + l15];
#pragma unroll
        for (int mi = 0; mi < 2; ++mi) {
#pragma unroll
            for (int reg = 0; reg < 4; ++reg) {
                int row = rowbase + wm * 32 + mi * 16 + lhi * 4 + reg;
                float v = acc[mi][ni][reg];
                float pl = v * alv;
                float pr = v * arv;
#pragma unroll
                for (int off = 8; off; off >>= 1) {
                    pl += __shfl_xor(pl, off);
                    pr += __shfl_xor(pr, off);
                }
                if (row < N) {
                    feat[((size_t)head * N + row) * 16 + l15] = f2bf(v);
                    if (l15 == 0) {
                        el[(size_t)head * N + row] = pl;
                        er[(size_t)head * N + row] = pr;
                    }
                }
            }
        }
    }
}

// ---------------- per-dst-node softmax + aggregation (head-sliced, XCD-affine) ----
// head = blockIdx % 8 -> all blocks for head h land on one XCD; its L2 only sees
// feat slice h (1.6MB) + el slice (200KB): resident (round-10 confirmed: FETCH
// 102MB -> 15MB). Round-10 lesson: per-node shfl reduces cost ~100us (10M
// bpermutes). So: 64 lanes = 8 NODES x 8 dim-pair lanes; each lane accumulates
// its own 2 dims + lsum over ALL of its node's edges in registers -> ZERO
// shuffles, no epilogue reduce. exp is redundant x8 (cheap, round-5-proven).
__global__ __launch_bounds__(256) void aggregate(const ushort* __restrict__ feat_s, // [8][N][16]
                                                 const float* __restrict__ el_t,    // [8][N]
                                                 const float* __restrict__ er_t,    // [8][N]
                                                 const int* __restrict__ rowstart,
                                                 const ushort* __restrict__ bucket,
                                                 const float* __restrict__ bias,    // [8][16]
                                                 ushort* __restrict__ out_s,        // [8][N][16]
                                                 int N, int do_relu) {
    int h = blockIdx.x & 7;
    int g = blockIdx.x >> 3;
    int w = threadIdx.x >> 6;
    int lane = threadIdx.x & 63;
    int ng = lane >> 3;  // node slot within wave (0..7)
    int dl = lane & 7;   // dim-pair lane (owns dims 2dl, 2dl+1 of 16)

    const float* elh = el_t + (size_t)h * N;
    const float* erh = er_t + (size_t)h * N;
    const unsigned int* fp = reinterpret_cast<const unsigned int*>(feat_s) + (size_t)h * N * 8 + dl;
    unsigned int* op = reinterpret_cast<unsigned int*>(out_s) + (size_t)h * N * 8 + dl;
    float2 bv = *reinterpret_cast<const float2*>(bias + h * 16 + dl * 2);

    // block handles 64 nodes: 2 passes of (4 waves x 8 nodes)
#pragma unroll
    for (int ni = 0; ni < 2; ++ni) {
        int n = g * 64 + ni * 32 + w * 8 + ng;
        if (n >= N) continue;
        int beg = rowstart[n];
        int end = rowstart[n + 1];
        float erv = erh[n];
        float lsum = 0.f, ax = 0.f, ay = 0.f;

        for (int j = beg; j < end; ++j) {
            int s = (int)bucket[j];            // 2B, 8-lane broadcast
            float e = elh[s] + erv;            // 4B broadcast gather (L2-resident)
            e = (e > 0.0f) ? e : LEAKY * e;
            float p = __expf(e);
            lsum += p;
            unsigned int u = fp[(size_t)s * 8]; // 4B x 8 lanes = one 32B segment
            ax = fmaf(p, bflo(u), ax);
            ay = fmaf(p, bfhi(u), ay);
        }

        float inv = (end > beg) ? 1.0f / lsum : 0.0f;
        float o0 = fmaf(ax, inv, bv.x);
        float o1 = fmaf(ay, inv, bv.y);
        if (do_relu) {
            o0 = fmaxf(o0, 0.f);
            o1 = fmaxf(o1, 0.f);
        }
        // 8 lanes x 4B = 32B/node, nodes consecutive -> 256B/wave contiguous
        op[(size_t)n * 8] = (unsigned int)f2bf(o0) | ((unsigned int)f2bf(o1) << 16);
    }
}

// ---------------- readout (h2 in sliced layout) ----------------
__global__ __launch_bounds__(256) void mean_reduce(const ushort* __restrict__ h,
                                                   float* __restrict__ meanbuf, int N) {
    int c = threadIdx.x & 127;
    int hh = c >> 4, d = c & 15;
    int rbase = blockIdx.x * 2 + (threadIdx.x >> 7);
    float s = 0.0f;
    for (int r = rbase; r < N; r += gridDim.x * 2)
        s += __uint_as_float((unsigned int)h[((size_t)hh * N + r) * 16 + d] << 16);
    atomicAdd(&meanbuf[c], s);
}

__global__ __launch_bounds__(64) void classifier(const float* __restrict__ meanbuf,
                                                 const float* __restrict__ Wc,
                                                 const float* __restrict__ bc,
                                                 float* __restrict__ outp, float invN) {
    int j = threadIdx.x;
    if (j < 10) {
        float s = 0.0f;
        for (int k = 0; k < 128; ++k) s += meanbuf[k] * invN * Wc[k * 10 + j];
        outp[j] = s + bc[j];
    }
}

// ---------------- launch ----------------

extern "C" void kernel_launch(void* const* d_in, const int* in_sizes, int n_in,
                              void* d_out, int out_size, void* d_ws, size_t ws_size,
                              hipStream_t stream) {
    const float* x   = (const float*)d_in[0];
    const int*   src = (const int*)d_in[1];
    const int*   dst = (const int*)d_in[2];
    const float* W1  = (const float*)d_in[3];
    const float* al1 = (const float*)d_in[4];
    const float* ar1 = (const float*)d_in[5];
    const float* b1  = (const float*)d_in[6];
    const float* W2  = (const float*)d_in[7];
    const float* al2 = (const float*)d_in[8];
    const float* ar2 = (const float*)d_in[9];
    const float* b2  = (const float*)d_in[10];
    const float* Wc  = (const float*)d_in[11];
    const float* bc  = (const float*)d_in[12];

    int N = in_sizes[0] / 128;
    int E = in_sizes[1];
    int NB = (N + (1 << BINB) - 1) >> BINB;

    size_t off = 0;
    auto alloc = [&](size_t bytes) -> void* {
        void* p = (char*)d_ws + off;
        off += (bytes + 255) & ~size_t(255);
        return p;
    };
    int*   bin_cnt    = (int*)alloc(sizeof(int) * NB);
    int*   binStart   = (int*)alloc(sizeof(int) * (NB + 1));
    int*   bin_cursor = (int*)alloc(sizeof(int) * NB);
    int*   rowstart   = (int*)alloc(sizeof(int) * (N + 1));
    unsigned int* coarse = (unsigned int*)alloc(sizeof(unsigned int) * E);
    ushort* bucket  = (ushort*)alloc(sizeof(ushort) * E);
    ushort* feat    = (ushort*)alloc(sizeof(ushort) * (size_t)N * 128);
    float* el       = (float*)alloc(sizeof(float) * N * 8);
    float* er       = (float*)alloc(sizeof(float) * N * 8);
    ushort* h1      = (ushort*)alloc(sizeof(ushort) * (size_t)N * 128);
    ushort* h2      = (ushort*)alloc(sizeof(ushort) * (size_t)N * 128);
    float* meanbuf  = (float*)alloc(sizeof(float) * 128);
    ushort* Wt1     = (ushort*)alloc(sizeof(ushort) * 128 * 128);
    ushort* Wt2     = (ushort*)alloc(sizeof(ushort) * 128 * 128);

    hipMemsetAsync(bin_cnt, 0, sizeof(int) * NB, stream);
    hipMemsetAsync(meanbuf, 0, sizeof(float) * 128, stream);

    int GB = ceil_div(E, TILE);
    int AGG = ceil_div(N, 64) * 8;  // 64-node groups x 8 heads, head = blockIdx%8

    bin_count<<<GB, 256, 0, stream>>>(dst, bin_cnt, E, NB);
    bin_scan<<<1, 256, 0, stream>>>(bin_cnt, binStart, bin_cursor, rowstart, NB, N, E);
    bin_scatter<<<GB, 256, 0, stream>>>(src, dst, bin_cursor, coarse, E);
    fine_csr<<<NB, 256, 0, stream>>>(coarse, binStart, rowstart, bucket, N);
    convert_w<<<128, 256, 0, stream>>>(W1, W2, Wt1, Wt2);

    // layer 1 (f32 input)
    gemm_attn_mfma<false><<<ceil_div(N, 64), 256, 0, stream>>>(x, Wt1, al1, ar1, feat, el, er, N);
    aggregate<<<AGG, 256, 0, stream>>>(feat, el, er, rowstart, bucket, b1, h1, N, 1);
    // layer 2 (sliced bf16 input)
    gemm_attn_mfma<true><<<ceil_div(N, 64), 256, 0, stream>>>(h1, Wt2, al2, ar2, feat, el, er, N);
    aggregate<<<AGG, 256, 0, stream>>>(feat, el, er, rowstart, bucket, b2, h2, N, 0);
    // readout
    mean_reduce<<<256, 256, 0, stream>>>(h2, meanbuf, N);
    classifier<<<1, 64, 0, stream>>>(meanbuf, Wc, bc, (float*)d_out, 1.0f / (float)N);
}

// Round 12
// 268.465 us; speedup vs baseline: 1.3886x; 1.1151x over previous
//
#include <hip/hip_runtime.h>
#include <hip/hip_bf16.h>

#define LEAKY 0.2f
#define BINB 8          // 256 nodes per bin (requires N <= 65536 for u16 packing)
#define TILE 2048       // edges per block in binning kernels
#define CAP 8192        // LDS bucket-segment capacity per bin (avg ~4081)

static inline int ceil_div(int a, int b) { return (a + b - 1) / b; }

typedef __bf16 bf16x8 __attribute__((ext_vector_type(8)));
typedef float f32x4 __attribute__((ext_vector_type(4)));

// f32 -> bf16 bits, round-to-nearest-even
__device__ __forceinline__ ushort f2bf(float f) {
    unsigned int x = __float_as_uint(f);
    unsigned int r = (x + 0x7fffu + ((x >> 16) & 1u)) >> 16;
    return (ushort)r;
}
__device__ __forceinline__ float bflo(unsigned int u) { return __uint_as_float(u << 16); }
__device__ __forceinline__ float bfhi(unsigned int u) { return __uint_as_float(u & 0xffff0000u); }

// ---------------- CSR build (two-level, coalesced writes) ----------------
// Round-4 lesson: one-pass random 4B scatter = 17x HBM write amplification.

__global__ __launch_bounds__(256) void bin_count(const int* __restrict__ dst,
                                                 int* __restrict__ bin_cnt, int E, int NB) {
    __shared__ int h[256];
    int t = threadIdx.x;
    h[t] = 0;
    __syncthreads();
    int base = blockIdx.x * TILE;
#pragma unroll
    for (int j = 0; j < TILE / 256; ++j) {
        int i = base + j * 256 + t;
        if (i < E) atomicAdd(&h[dst[i] >> BINB], 1);
    }
    __syncthreads();
    if (t < NB && h[t]) atomicAdd(&bin_cnt[t], h[t]);
}

__global__ __launch_bounds__(256) void bin_scan(const int* __restrict__ bin_cnt,
                                                int* __restrict__ binStart,
                                                int* __restrict__ bin_cursor,
                                                int* __restrict__ rowstart,
                                                int NB, int N, int E) {
    __shared__ int s[256];
    int t = threadIdx.x;
    int v = (t < NB) ? bin_cnt[t] : 0;
    s[t] = v;
    __syncthreads();
    for (int off = 1; off < 256; off <<= 1) {
        int x = (t >= off) ? s[t - off] : 0;
        __syncthreads();
        s[t] += x;
        __syncthreads();
    }
    int excl = s[t] - v;
    if (t < NB) {
        binStart[t] = excl;
        bin_cursor[t] = excl;
        if (t == NB - 1) binStart[NB] = excl + v;
    }
    if (t == 0) rowstart[N] = E;
}

__global__ __launch_bounds__(256) void bin_scatter(const int* __restrict__ src,
                                                   const int* __restrict__ dst,
                                                   int* __restrict__ bin_cursor,
                                                   unsigned int* __restrict__ coarse, int E) {
    __shared__ int hist[256], scn[256], gbase[256], lcur[256];
    __shared__ unsigned int outp[TILE];
    __shared__ int gidx[TILE];
    int t = threadIdx.x;
    hist[t] = 0;
    __syncthreads();
    int base = blockIdx.x * TILE;
    int dloc[TILE / 256];
#pragma unroll
    for (int j = 0; j < TILE / 256; ++j) {
        int i = base + j * 256 + t;
        int d = (i < E) ? dst[i] : -1;
        dloc[j] = d;
        if (d >= 0) atomicAdd(&hist[d >> BINB], 1);
    }
    __syncthreads();
    int hv = hist[t];
    scn[t] = hv;
    __syncthreads();
    for (int off = 1; off < 256; off <<= 1) {
        int x = (t >= off) ? scn[t - off] : 0;
        __syncthreads();
        scn[t] += x;
        __syncthreads();
    }
    int excl = scn[t] - hv;
    if (hv > 0) gbase[t] = atomicAdd(&bin_cursor[t], hv);
    lcur[t] = excl;
    scn[t] = excl;
    __syncthreads();
#pragma unroll
    for (int j = 0; j < TILE / 256; ++j) {
        int i = base + j * 256 + t;
        int d = dloc[j];
        if (d >= 0) {
            int b = d >> BINB;
            int pos = atomicAdd(&lcur[b], 1);
            outp[pos] = (unsigned int)src[i] | ((unsigned int)(d & ((1 << BINB) - 1)) << 16);
            gidx[pos] = gbase[b] + (pos - scn[b]);
        }
    }
    __syncthreads();
    int cnt = min(TILE, E - base);
    for (int j = t; j < cnt; j += 256) coarse[gidx[j]] = outp[j];
}

__global__ __launch_bounds__(256) void fine_csr(const unsigned int* __restrict__ coarse,
                                                const int* __restrict__ binStart,
                                                int* __restrict__ rowstart,
                                                ushort* __restrict__ bucket, int N) {
    __shared__ int hist[256], scn[256], cur[256];
    __shared__ ushort sb[CAP];
    int b = blockIdx.x, t = threadIdx.x;
    int e0 = binStart[b], e1 = binStart[b + 1];
    int cnt = e1 - e0;
    hist[t] = 0;
    __syncthreads();
    for (int j = e0 + t; j < e1; j += 256) atomicAdd(&hist[coarse[j] >> 16], 1);
    __syncthreads();
    int hv = hist[t];
    scn[t] = hv;
    __syncthreads();
    for (int off = 1; off < 256; off <<= 1) {
        int x = (t >= off) ? scn[t - off] : 0;
        __syncthreads();
        scn[t] += x;
        __syncthreads();
    }
    int excl = scn[t] - hv;
    int n = (b << BINB) + t;
    if (n < N) rowstart[n] = e0 + excl;
    cur[t] = excl;
    __syncthreads();
    bool fit = (cnt <= CAP);
    for (int j = e0 + t; j < e1; j += 256) {
        unsigned int p = coarse[j];
        int dl = p >> 16;
        int pos = atomicAdd(&cur[dl], 1);
        ushort sv = (ushort)(p & 0xffffu);
        if (fit) sb[pos] = sv;
        else bucket[e0 + pos] = sv;
    }
    __syncthreads();
    if (fit)
        for (int j = t; j < cnt; j += 256) bucket[e0 + j] = sb[j];
}

// ---------------- W convert: Wt[n][k] = bf16(W[k][n]) ----------------
__global__ __launch_bounds__(256) void convert_w(const float* __restrict__ W1,
                                                 const float* __restrict__ W2,
                                                 ushort* __restrict__ Wt1,
                                                 ushort* __restrict__ Wt2) {
    int idx = blockIdx.x * 256 + threadIdx.x;
    const float* W = (idx < 16384) ? W1 : W2;
    ushort* O = (idx < 16384) ? Wt1 : Wt2;
    int i = idx & 16383;
    int k = i >> 7, n = i & 127;
    O[n * 128 + k] = f2bf(W[i]);
}

// ---------------- MFMA GEMM + attention coefficients ----------------
// Block 64x128, 4 waves (2M x 2N). Outputs in HEAD-SLICED layouts:
//   feat [8][N][16] bf16, el/er [8][N] f32  (enables XCD-local aggregation).
#define LDK 136
template <bool BF16IN>
__global__ __launch_bounds__(256) void gemm_attn_mfma(const void* __restrict__ in_,
                                                      const ushort* __restrict__ Wt,
                                                      const float* __restrict__ al,
                                                      const float* __restrict__ ar,
                                                      ushort* __restrict__ feat,
                                                      float* __restrict__ el,
                                                      float* __restrict__ er, int N) {
    __shared__ ushort sA[64 * LDK];
    int tid = threadIdx.x;
    int rowbase = blockIdx.x * 64;

    if (BF16IN) {
        const ushort* in = (const ushort*)in_;  // sliced [8][N][16]
#pragma unroll
        for (int i = 0; i < 4; ++i) {
            int idx8 = i * 256 + tid;
            int flat = idx8 * 8;
            int row = flat >> 7, col = flat & 127;   // col%16 in {0,8}
            int grow = rowbase + row;
            int hh = col >> 4, d = col & 15;
            uint4 v = make_uint4(0, 0, 0, 0);
            if (grow < N)
                v = *reinterpret_cast<const uint4*>(in + ((size_t)hh * N + grow) * 16 + d);
            *reinterpret_cast<uint4*>(&sA[row * LDK + col]) = v;
        }
    } else {
        const float* in = (const float*)in_;
#pragma unroll
        for (int i = 0; i < 8; ++i) {
            int idx4 = i * 256 + tid;
            int flat = idx4 * 4;
            int row = flat >> 7, col = flat & 127;
            int grow = rowbase + row;
            float4 v = make_float4(0.f, 0.f, 0.f, 0.f);
            if (grow < N) v = *reinterpret_cast<const float4*>(in + (size_t)grow * 128 + col);
            uint2 w;
            w.x = (unsigned int)f2bf(v.x) | ((unsigned int)f2bf(v.y) << 16);
            w.y = (unsigned int)f2bf(v.z) | ((unsigned int)f2bf(v.w) << 16);
            *reinterpret_cast<uint2*>(&sA[row * LDK + col]) = w;
        }
    }
    __syncthreads();

    int wid = tid >> 6;
    int lane = tid & 63;
    int wm = wid >> 1;
    int wn = wid & 1;
    int l15 = lane & 15;
    int lhi = lane >> 4;

    f32x4 acc[2][4] = {};
    const ushort* wb = Wt + (size_t)(wn * 64 + l15) * 128 + lhi * 8;
    const ushort* a0p = &sA[(wm * 32 + l15) * LDK + lhi * 8];
    const ushort* a1p = &sA[(wm * 32 + 16 + l15) * LDK + lhi * 8];

#pragma unroll
    for (int ks = 0; ks < 4; ++ks) {
        bf16x8 a0 = *reinterpret_cast<const bf16x8*>(a0p + ks * 32);
        bf16x8 a1 = *reinterpret_cast<const bf16x8*>(a1p + ks * 32);
#pragma unroll
        for (int ni = 0; ni < 4; ++ni) {
            bf16x8 b = *reinterpret_cast<const bf16x8*>(wb + ni * 16 * 128 + ks * 32);
            acc[0][ni] = __builtin_amdgcn_mfma_f32_16x16x32_bf16(a0, b, acc[0][ni], 0, 0, 0);
            acc[1][ni] = __builtin_amdgcn_mfma_f32_16x16x32_bf16(a1, b, acc[1][ni], 0, 0, 0);
        }
    }

#pragma unroll
    for (int ni = 0; ni < 4; ++ni) {
        int head = wn * 4 + ni;
        float alv = al[head * 16 + l15];
        float arv = ar[head * 16 + l15];
#pragma unroll
        for (int mi = 0; mi < 2; ++mi) {
#pragma unroll
            for (int reg = 0; reg < 4; ++reg) {
                int row = rowbase + wm * 32 + mi * 16 + lhi * 4 + reg;
                float v = acc[mi][ni][reg];
                float pl = v * alv;
                float pr = v * arv;
#pragma unroll
                for (int off = 8; off; off >>= 1) {
                    pl += __shfl_xor(pl, off);
                    pr += __shfl_xor(pr, off);
                }
                if (row < N) {
                    feat[((size_t)head * N + row) * 16 + l15] = f2bf(v);
                    if (l15 == 0) {
                        el[(size_t)head * N + row] = pl;
                        er[(size_t)head * N + row] = pr;
                    }
                }
            }
        }
    }
}

// ---------------- per-dst-node softmax + aggregation (head-sliced, XCD-affine) ----
// head = blockIdx % 8 -> all blocks for head h share one XCD whose L2 only sees
// feat slice h (1.6MB) + el slice (200KB) -> resident (FETCH 102MB -> 15MB,
// round-10/11 confirmed). 64 lanes = 8 NODES x 8 dim-pair lanes; each lane owns
// 2 dims + lsum in registers: zero shuffles (round-10 lesson: 10M bpermutes =
// 100us). Edge loop unrolled x4 with BATCHED INDEPENDENT loads (round-11 lesson:
// serial bucket->el->feat chain at VGPR=12 left 83us of latency stalls; round-5
// proved 8-in-flight gathers fix this).
__global__ __launch_bounds__(256) void aggregate(const ushort* __restrict__ feat_s, // [8][N][16]
                                                 const float* __restrict__ el_t,    // [8][N]
                                                 const float* __restrict__ er_t,    // [8][N]
                                                 const int* __restrict__ rowstart,
                                                 const ushort* __restrict__ bucket,
                                                 const float* __restrict__ bias,    // [8][16]
                                                 ushort* __restrict__ out_s,        // [8][N][16]
                                                 int N, int do_relu) {
    int h = blockIdx.x & 7;
    int g = blockIdx.x >> 3;
    int w = threadIdx.x >> 6;
    int lane = threadIdx.x & 63;
    int ng = lane >> 3;  // node slot within wave (0..7)
    int dl = lane & 7;   // dim-pair lane (owns dims 2dl, 2dl+1 of 16)

    const float* elh = el_t + (size_t)h * N;
    const float* erh = er_t + (size_t)h * N;
    const unsigned int* fp = reinterpret_cast<const unsigned int*>(feat_s) + (size_t)h * N * 8 + dl;
    unsigned int* op = reinterpret_cast<unsigned int*>(out_s) + (size_t)h * N * 8 + dl;
    float2 bv = *reinterpret_cast<const float2*>(bias + h * 16 + dl * 2);

    // block handles 64 nodes: 2 passes of (4 waves x 8 nodes)
#pragma unroll
    for (int ni = 0; ni < 2; ++ni) {
        int n = g * 64 + ni * 32 + w * 8 + ng;
        if (n >= N) continue;
        int beg = rowstart[n];
        int end = rowstart[n + 1];
        float erv = erh[n];
        float lsum = 0.f, ax = 0.f, ay = 0.f;

        int j = beg;
        for (; j + 4 <= end; j += 4) {
            // batch-4: all loads independent, 12 in flight per wait
            int s0 = (int)bucket[j + 0];
            int s1 = (int)bucket[j + 1];
            int s2 = (int)bucket[j + 2];
            int s3 = (int)bucket[j + 3];
            float e0 = elh[s0], e1 = elh[s1], e2 = elh[s2], e3 = elh[s3];
            unsigned int u0 = fp[(size_t)s0 * 8];
            unsigned int u1 = fp[(size_t)s1 * 8];
            unsigned int u2 = fp[(size_t)s2 * 8];
            unsigned int u3 = fp[(size_t)s3 * 8];
            e0 += erv; e1 += erv; e2 += erv; e3 += erv;
            e0 = (e0 > 0.f) ? e0 : LEAKY * e0;
            e1 = (e1 > 0.f) ? e1 : LEAKY * e1;
            e2 = (e2 > 0.f) ? e2 : LEAKY * e2;
            e3 = (e3 > 0.f) ? e3 : LEAKY * e3;
            float p0 = __expf(e0), p1 = __expf(e1), p2 = __expf(e2), p3 = __expf(e3);
            lsum += (p0 + p1) + (p2 + p3);
            ax = fmaf(p0, bflo(u0), ax);  ay = fmaf(p0, bfhi(u0), ay);
            ax = fmaf(p1, bflo(u1), ax);  ay = fmaf(p1, bfhi(u1), ay);
            ax = fmaf(p2, bflo(u2), ax);  ay = fmaf(p2, bfhi(u2), ay);
            ax = fmaf(p3, bflo(u3), ax);  ay = fmaf(p3, bfhi(u3), ay);
        }
        for (; j < end; ++j) {
            int s = (int)bucket[j];
            float e = elh[s] + erv;
            e = (e > 0.f) ? e : LEAKY * e;
            float p = __expf(e);
            unsigned int u = fp[(size_t)s * 8];
            lsum += p;
            ax = fmaf(p, bflo(u), ax);
            ay = fmaf(p, bfhi(u), ay);
        }

        float inv = (end > beg) ? 1.0f / lsum : 0.0f;
        float o0 = fmaf(ax, inv, bv.x);
        float o1 = fmaf(ay, inv, bv.y);
        if (do_relu) {
            o0 = fmaxf(o0, 0.f);
            o1 = fmaxf(o1, 0.f);
        }
        // 8 lanes x 4B = 32B/node, nodes consecutive -> 256B/wave contiguous
        op[(size_t)n * 8] = (unsigned int)f2bf(o0) | ((unsigned int)f2bf(o1) << 16);
    }
}

// ---------------- readout (h2 in sliced layout) ----------------
__global__ __launch_bounds__(256) void mean_reduce(const ushort* __restrict__ h,
                                                   float* __restrict__ meanbuf, int N) {
    int c = threadIdx.x & 127;
    int hh = c >> 4, d = c & 15;
    int rbase = blockIdx.x * 2 + (threadIdx.x >> 7);
    float s = 0.0f;
    for (int r = rbase; r < N; r += gridDim.x * 2)
        s += __uint_as_float((unsigned int)h[((size_t)hh * N + r) * 16 + d] << 16);
    atomicAdd(&meanbuf[c], s);
}

__global__ __launch_bounds__(64) void classifier(const float* __restrict__ meanbuf,
                                                 const float* __restrict__ Wc,
                                                 const float* __restrict__ bc,
                                                 float* __restrict__ outp, float invN) {
    int j = threadIdx.x;
    if (j < 10) {
        float s = 0.0f;
        for (int k = 0; k < 128; ++k) s += meanbuf[k] * invN * Wc[k * 10 + j];
        outp[j] = s + bc[j];
    }
}

// ---------------- launch ----------------

extern "C" void kernel_launch(void* const* d_in, const int* in_sizes, int n_in,
                              void* d_out, int out_size, void* d_ws, size_t ws_size,
                              hipStream_t stream) {
    const float* x   = (const float*)d_in[0];
    const int*   src = (const int*)d_in[1];
    const int*   dst = (const int*)d_in[2];
    const float* W1  = (const float*)d_in[3];
    const float* al1 = (const float*)d_in[4];
    const float* ar1 = (const float*)d_in[5];
    const float* b1  = (const float*)d_in[6];
    const float* W2  = (const float*)d_in[7];
    const float* al2 = (const float*)d_in[8];
    const float* ar2 = (const float*)d_in[9];
    const float* b2  = (const float*)d_in[10];
    const float* Wc  = (const float*)d_in[11];
    const float* bc  = (const float*)d_in[12];

    int N = in_sizes[0] / 128;
    int E = in_sizes[1];
    int NB = (N + (1 << BINB) - 1) >> BINB;

    size_t off = 0;
    auto alloc = [&](size_t bytes) -> void* {
        void* p = (char*)d_ws + off;
        off += (bytes + 255) & ~size_t(255);
        return p;
    };
    int*   bin_cnt    = (int*)alloc(sizeof(int) * NB);
    int*   binStart   = (int*)alloc(sizeof(int) * (NB + 1));
    int*   bin_cursor = (int*)alloc(sizeof(int) * NB);
    int*   rowstart   = (int*)alloc(sizeof(int) * (N + 1));
    unsigned int* coarse = (unsigned int*)alloc(sizeof(unsigned int) * E);
    ushort* bucket  = (ushort*)alloc(sizeof(ushort) * E);
    ushort* feat    = (ushort*)alloc(sizeof(ushort) * (size_t)N * 128);
    float* el       = (float*)alloc(sizeof(float) * N * 8);
    float* er       = (float*)alloc(sizeof(float) * N * 8);
    ushort* h1      = (ushort*)alloc(sizeof(ushort) * (size_t)N * 128);
    ushort* h2      = (ushort*)alloc(sizeof(ushort) * (size_t)N * 128);
    float* meanbuf  = (float*)alloc(sizeof(float) * 128);
    ushort* Wt1     = (ushort*)alloc(sizeof(ushort) * 128 * 128);
    ushort* Wt2     = (ushort*)alloc(sizeof(ushort) * 128 * 128);

    hipMemsetAsync(bin_cnt, 0, sizeof(int) * NB, stream);
    hipMemsetAsync(meanbuf, 0, sizeof(float) * 128, stream);

    int GB = ceil_div(E, TILE);
    int AGG = ceil_div(N, 64) * 8;  // 64-node groups x 8 heads, head = blockIdx%8

    bin_count<<<GB, 256, 0, stream>>>(dst, bin_cnt, E, NB);
    bin_scan<<<1, 256, 0, stream>>>(bin_cnt, binStart, bin_cursor, rowstart, NB, N, E);
    bin_scatter<<<GB, 256, 0, stream>>>(src, dst, bin_cursor, coarse, E);
    fine_csr<<<NB, 256, 0, stream>>>(coarse, binStart, rowstart, bucket, N);
    convert_w<<<128, 256, 0, stream>>>(W1, W2, Wt1, Wt2);

    // layer 1 (f32 input)
    gemm_attn_mfma<false><<<ceil_div(N, 64), 256, 0, stream>>>(x, Wt1, al1, ar1, feat, el, er, N);
    aggregate<<<AGG, 256, 0, stream>>>(feat, el, er, rowstart, bucket, b1, h1, N, 1);
    // layer 2 (sliced bf16 input)
    gemm_attn_mfma<true><<<ceil_div(N, 64), 256, 0, stream>>>(h1, Wt2, al2, ar2, feat, el, er, N);
    aggregate<<<AGG, 256, 0, stream>>>(feat, el, er, rowstart, bucket, b2, h2, N, 0);
    // readout
    mean_reduce<<<256, 256, 0, stream>>>(h2, meanbuf, N);
    classifier<<<1, 64, 0, stream>>>(meanbuf, Wc, bc, (float*)d_out, 1.0f / (float)N);
}

// Round 13
// 240.425 us; speedup vs baseline: 1.5505x; 1.1166x over previous
//
#include <hip/hip_runtime.h>
#include <hip/hip_bf16.h>

#define LEAKY 0.2f
#define BINB 8          // 256 nodes per bin (requires N <= 65536 for u16 packing)
#define TILE 2048       // edges per block in binning kernels
#define CAP 8192        // LDS bucket-segment capacity per bin (avg ~4081)

static inline int ceil_div(int a, int b) { return (a + b - 1) / b; }

typedef __bf16 bf16x8 __attribute__((ext_vector_type(8)));
typedef float f32x4 __attribute__((ext_vector_type(4)));

// f32 -> bf16 bits, round-to-nearest-even
__device__ __forceinline__ ushort f2bf(float f) {
    unsigned int x = __float_as_uint(f);
    unsigned int r = (x + 0x7fffu + ((x >> 16) & 1u)) >> 16;
    return (ushort)r;
}
__device__ __forceinline__ float bflo(unsigned int u) { return __uint_as_float(u << 16); }
__device__ __forceinline__ float bfhi(unsigned int u) { return __uint_as_float(u & 0xffff0000u); }

// ---------------- CSR build (two-level, coalesced writes) ----------------
// Round-4 lesson: one-pass random 4B scatter = 17x HBM write amplification.

__global__ __launch_bounds__(256) void bin_count(const int* __restrict__ dst,
                                                 int* __restrict__ bin_cnt, int E, int NB) {
    __shared__ int h[256];
    int t = threadIdx.x;
    h[t] = 0;
    __syncthreads();
    int base = blockIdx.x * TILE;
#pragma unroll
    for (int j = 0; j < TILE / 256; ++j) {
        int i = base + j * 256 + t;
        if (i < E) atomicAdd(&h[dst[i] >> BINB], 1);
    }
    __syncthreads();
    if (t < NB && h[t]) atomicAdd(&bin_cnt[t], h[t]);
}

__global__ __launch_bounds__(256) void bin_scan(const int* __restrict__ bin_cnt,
                                                int* __restrict__ binStart,
                                                int* __restrict__ bin_cursor,
                                                int* __restrict__ rowstart,
                                                int NB, int N, int E) {
    __shared__ int s[256];
    int t = threadIdx.x;
    int v = (t < NB) ? bin_cnt[t] : 0;
    s[t] = v;
    __syncthreads();
    for (int off = 1; off < 256; off <<= 1) {
        int x = (t >= off) ? s[t - off] : 0;
        __syncthreads();
        s[t] += x;
        __syncthreads();
    }
    int excl = s[t] - v;
    if (t < NB) {
        binStart[t] = excl;
        bin_cursor[t] = excl;
        if (t == NB - 1) binStart[NB] = excl + v;
    }
    if (t == 0) rowstart[N] = E;
}

__global__ __launch_bounds__(256) void bin_scatter(const int* __restrict__ src,
                                                   const int* __restrict__ dst,
                                                   int* __restrict__ bin_cursor,
                                                   unsigned int* __restrict__ coarse, int E) {
    __shared__ int hist[256], scn[256], gbase[256], lcur[256];
    __shared__ unsigned int outp[TILE];
    __shared__ int gidx[TILE];
    int t = threadIdx.x;
    hist[t] = 0;
    __syncthreads();
    int base = blockIdx.x * TILE;
    int dloc[TILE / 256];
#pragma unroll
    for (int j = 0; j < TILE / 256; ++j) {
        int i = base + j * 256 + t;
        int d = (i < E) ? dst[i] : -1;
        dloc[j] = d;
        if (d >= 0) atomicAdd(&hist[d >> BINB], 1);
    }
    __syncthreads();
    int hv = hist[t];
    scn[t] = hv;
    __syncthreads();
    for (int off = 1; off < 256; off <<= 1) {
        int x = (t >= off) ? scn[t - off] : 0;
        __syncthreads();
        scn[t] += x;
        __syncthreads();
    }
    int excl = scn[t] - hv;
    if (hv > 0) gbase[t] = atomicAdd(&bin_cursor[t], hv);
    lcur[t] = excl;
    scn[t] = excl;
    __syncthreads();
#pragma unroll
    for (int j = 0; j < TILE / 256; ++j) {
        int i = base + j * 256 + t;
        int d = dloc[j];
        if (d >= 0) {
            int b = d >> BINB;
            int pos = atomicAdd(&lcur[b], 1);
            outp[pos] = (unsigned int)src[i] | ((unsigned int)(d & ((1 << BINB) - 1)) << 16);
            gidx[pos] = gbase[b] + (pos - scn[b]);
        }
    }
    __syncthreads();
    int cnt = min(TILE, E - base);
    for (int j = t; j < cnt; j += 256) coarse[gidx[j]] = outp[j];
}

// Also emits dst16[j] = global dst node of CSR slot j (needed by edge_weights).
__global__ __launch_bounds__(256) void fine_csr(const unsigned int* __restrict__ coarse,
                                                const int* __restrict__ binStart,
                                                int* __restrict__ rowstart,
                                                ushort* __restrict__ bucket,
                                                ushort* __restrict__ dst16, int N) {
    __shared__ int hist[256], scn[256], cur[256];
    __shared__ ushort sb[CAP];
    __shared__ ushort db[CAP];
    int b = blockIdx.x, t = threadIdx.x;
    int e0 = binStart[b], e1 = binStart[b + 1];
    int cnt = e1 - e0;
    hist[t] = 0;
    __syncthreads();
    for (int j = e0 + t; j < e1; j += 256) atomicAdd(&hist[coarse[j] >> 16], 1);
    __syncthreads();
    int hv = hist[t];
    scn[t] = hv;
    __syncthreads();
    for (int off = 1; off < 256; off <<= 1) {
        int x = (t >= off) ? scn[t - off] : 0;
        __syncthreads();
        scn[t] += x;
        __syncthreads();
    }
    int excl = scn[t] - hv;
    int n = (b << BINB) + t;
    if (n < N) rowstart[n] = e0 + excl;
    cur[t] = excl;
    __syncthreads();
    bool fit = (cnt <= CAP);
    for (int j = e0 + t; j < e1; j += 256) {
        unsigned int p = coarse[j];
        int dl = p >> 16;
        int pos = atomicAdd(&cur[dl], 1);
        ushort sv = (ushort)(p & 0xffffu);
        ushort dv = (ushort)((b << BINB) | dl);
        if (fit) {
            sb[pos] = sv;
            db[pos] = dv;
        } else {
            bucket[e0 + pos] = sv;
            dst16[e0 + pos] = dv;
        }
    }
    __syncthreads();
    if (fit) {
        for (int j = t; j < cnt; j += 256) {
            bucket[e0 + j] = sb[j];
            dst16[e0 + j] = db[j];
        }
    }
}

// ---------------- W convert: Wt[n][k] = bf16(W[k][n]) ----------------
__global__ __launch_bounds__(256) void convert_w(const float* __restrict__ W1,
                                                 const float* __restrict__ W2,
                                                 ushort* __restrict__ Wt1,
                                                 ushort* __restrict__ Wt2) {
    int idx = blockIdx.x * 256 + threadIdx.x;
    const float* W = (idx < 16384) ? W1 : W2;
    ushort* O = (idx < 16384) ? Wt1 : Wt2;
    int i = idx & 16383;
    int k = i >> 7, n = i & 127;
    O[n * 128 + k] = f2bf(W[i]);
}

// ---------------- MFMA GEMM + attention coefficients (flat layouts) ----------------
// Block 64x128, 4 waves (2M x 2N). feat [N][128] bf16; el/er [N][8] f32.
#define LDK 136
template <bool BF16IN>
__global__ __launch_bounds__(256) void gemm_attn_mfma(const void* __restrict__ in_,
                                                      const ushort* __restrict__ Wt,
                                                      const float* __restrict__ al,
                                                      const float* __restrict__ ar,
                                                      ushort* __restrict__ feat,
                                                      float* __restrict__ el,
                                                      float* __restrict__ er, int N) {
    __shared__ ushort sA[64 * LDK];
    int tid = threadIdx.x;
    int rowbase = blockIdx.x * 64;

    if (BF16IN) {
        const ushort* in = (const ushort*)in_;
#pragma unroll
        for (int i = 0; i < 4; ++i) {
            int idx8 = i * 256 + tid;
            int flat = idx8 * 8;
            int row = flat >> 7, col = flat & 127;
            int grow = rowbase + row;
            uint4 v = make_uint4(0, 0, 0, 0);
            if (grow < N) v = *reinterpret_cast<const uint4*>(in + (size_t)grow * 128 + col);
            *reinterpret_cast<uint4*>(&sA[row * LDK + col]) = v;
        }
    } else {
        const float* in = (const float*)in_;
#pragma unroll
        for (int i = 0; i < 8; ++i) {
            int idx4 = i * 256 + tid;
            int flat = idx4 * 4;
            int row = flat >> 7, col = flat & 127;
            int grow = rowbase + row;
            float4 v = make_float4(0.f, 0.f, 0.f, 0.f);
            if (grow < N) v = *reinterpret_cast<const float4*>(in + (size_t)grow * 128 + col);
            uint2 w;
            w.x = (unsigned int)f2bf(v.x) | ((unsigned int)f2bf(v.y) << 16);
            w.y = (unsigned int)f2bf(v.z) | ((unsigned int)f2bf(v.w) << 16);
            *reinterpret_cast<uint2*>(&sA[row * LDK + col]) = w;
        }
    }
    __syncthreads();

    int wid = tid >> 6;
    int lane = tid & 63;
    int wm = wid >> 1;
    int wn = wid & 1;
    int l15 = lane & 15;
    int lhi = lane >> 4;

    f32x4 acc[2][4] = {};
    const ushort* wb = Wt + (size_t)(wn * 64 + l15) * 128 + lhi * 8;
    const ushort* a0p = &sA[(wm * 32 + l15) * LDK + lhi * 8];
    const ushort* a1p = &sA[(wm * 32 + 16 + l15) * LDK + lhi * 8];

#pragma unroll
    for (int ks = 0; ks < 4; ++ks) {
        bf16x8 a0 = *reinterpret_cast<const bf16x8*>(a0p + ks * 32);
        bf16x8 a1 = *reinterpret_cast<const bf16x8*>(a1p + ks * 32);
#pragma unroll
        for (int ni = 0; ni < 4; ++ni) {
            bf16x8 b = *reinterpret_cast<const bf16x8*>(wb + ni * 16 * 128 + ks * 32);
            acc[0][ni] = __builtin_amdgcn_mfma_f32_16x16x32_bf16(a0, b, acc[0][ni], 0, 0, 0);
            acc[1][ni] = __builtin_amdgcn_mfma_f32_16x16x32_bf16(a1, b, acc[1][ni], 0, 0, 0);
        }
    }

#pragma unroll
    for (int ni = 0; ni < 4; ++ni) {
        int head = wn * 4 + ni;
        float alv = al[head * 16 + l15];
        float arv = ar[head * 16 + l15];
#pragma unroll
        for (int mi = 0; mi < 2; ++mi) {
#pragma unroll
            for (int reg = 0; reg < 4; ++reg) {
                int row = rowbase + wm * 32 + mi * 16 + lhi * 4 + reg;
                float v = acc[mi][ni][reg];
                float pl = v * alv;
                float pr = v * arv;
#pragma unroll
                for (int off = 8; off; off >>= 1) {
                    pl += __shfl_xor(pl, off);
                    pr += __shfl_xor(pr, off);
                }
                if (row < N) {
                    feat[(size_t)row * 128 + head * 16 + l15] = f2bf(v);
                    if (l15 == 0) {
                        el[row * 8 + head] = pl;
                        er[row * 8 + head] = pr;
                    }
                }
            }
        }
    }
}

// ---------------- edge weights: w[j][h] = exp(leaky(el[src_j]+er[dst_j])) ----------
// Edge-parallel, fully coalesced, zero divergence. Moves exp+leaky+el/er gathers
// OUT of the per-node aggregate loop (round-12 lesson: the x8 per-head edge walk
// inflated wave-instructions 8x; round-5's all-heads walk + this precompute makes
// the aggregate inner loop pure fma).
__global__ __launch_bounds__(256) void edge_weights(const ushort* __restrict__ bucket,
                                                    const ushort* __restrict__ dst16,
                                                    const float* __restrict__ el,
                                                    const float* __restrict__ er,
                                                    float* __restrict__ w, int E) {
    int tid0 = blockIdx.x * 256 + threadIdx.x;
    int h = tid0 & 7;
    int stride = (gridDim.x * 256) >> 3;
    for (int j = tid0 >> 3; j < E; j += stride) {
        int s = (int)bucket[j];   // 8 threads share j -> broadcast
        int d = (int)dst16[j];
        float x = el[s * 8 + h] + er[d * 8 + h];   // 32B contiguous per edge
        x = (x > 0.f) ? x : LEAKY * x;
        w[(size_t)j * 8 + h] = __expf(x);          // coalesced 256B per 8 edges
    }
}

// ---------------- per-dst-node aggregation (flat, all heads per walk) ----------------
// Round-5 structure: one wave per node; lane owns dims 2*lane,2*lane+1 (head =
// lane>>3); each edge visited ONCE serving all 8 heads. Weights precomputed ->
// inner loop = shfl + 2 loads + 2 fma. Denominator: lsum accumulates the broadcast
// w identically in all 8 lanes of a head-group -> no reduce. Batch-8 ILP (16
// loads in flight). Zero shuffle-reduces, zero exp, zero divergence.
__global__ __launch_bounds__(256) void aggregate(const ushort* __restrict__ feat,
                                                 const float* __restrict__ w,
                                                 const int* __restrict__ rowstart,
                                                 const ushort* __restrict__ bucket,
                                                 const float* __restrict__ bias,
                                                 ushort* __restrict__ out,
                                                 int N, int do_relu) {
    int wid = (blockIdx.x * 256 + threadIdx.x) >> 6;
    int lane = threadIdx.x & 63;
    if (wid >= N) return;
    int h = lane >> 3;
    int beg = rowstart[wid];
    int end = rowstart[wid + 1];

    const unsigned int* fp = reinterpret_cast<const unsigned int*>(feat) + lane;
    const float* wh = w + h;

    float lsum = 0.f, ax = 0.f, ay = 0.f;

    for (int base = beg; base < end; base += 64) {
        int cnt = min(end - base, 64);
        int myedge = base + lane;
        int sv = (myedge < end) ? (int)bucket[myedge] : 0;  // coalesced 128B per 64 edges
        int k = 0;
        for (; k + 8 <= cnt; k += 8) {
            int ss[8];
            float ww[8];
            unsigned int uu[8];
#pragma unroll
            for (int q = 0; q < 8; ++q) ss[q] = __shfl(sv, k + q);
#pragma unroll
            for (int q = 0; q < 8; ++q) ww[q] = wh[(size_t)(base + k + q) * 8];  // 32B bcast
#pragma unroll
            for (int q = 0; q < 8; ++q) uu[q] = fp[(size_t)ss[q] * 64];          // 256B row
#pragma unroll
            for (int q = 0; q < 8; ++q) {
                lsum += ww[q];
                ax = fmaf(ww[q], bflo(uu[q]), ax);
                ay = fmaf(ww[q], bfhi(uu[q]), ay);
            }
        }
        for (; k < cnt; ++k) {
            int s = __shfl(sv, k);
            float wv = wh[(size_t)(base + k) * 8];
            unsigned int u = fp[(size_t)s * 64];
            lsum += wv;
            ax = fmaf(wv, bflo(u), ax);
            ay = fmaf(wv, bfhi(u), ay);
        }
    }

    float inv = (end > beg) ? 1.0f / lsum : 0.0f;
    int c = lane * 2;
    float2 bv = *reinterpret_cast<const float2*>(bias + c);
    float ox = fmaf(ax, inv, bv.x);
    float oy = fmaf(ay, inv, bv.y);
    if (do_relu) {
        ox = fmaxf(ox, 0.f);
        oy = fmaxf(oy, 0.f);
    }
    reinterpret_cast<unsigned int*>(out)[(size_t)wid * 64 + lane] =
        (unsigned int)f2bf(ox) | ((unsigned int)f2bf(oy) << 16);
}

// ---------------- readout (flat bf16) ----------------
__global__ __launch_bounds__(256) void mean_reduce(const ushort* __restrict__ h,
                                                   float* __restrict__ meanbuf, int N) {
    int c = threadIdx.x & 127;
    int rbase = blockIdx.x * 2 + (threadIdx.x >> 7);
    float s = 0.0f;
    for (int r = rbase; r < N; r += gridDim.x * 2)
        s += __uint_as_float((unsigned int)h[(size_t)r * 128 + c] << 16);
    atomicAdd(&meanbuf[c], s);
}

__global__ __launch_bounds__(64) void classifier(const float* __restrict__ meanbuf,
                                                 const float* __restrict__ Wc,
                                                 const float* __restrict__ bc,
                                                 float* __restrict__ outp, float invN) {
    int j = threadIdx.x;
    if (j < 10) {
        float s = 0.0f;
        for (int k = 0; k < 128; ++k) s += meanbuf[k] * invN * Wc[k * 10 + j];
        outp[j] = s + bc[j];
    }
}

// ---------------- launch ----------------

extern "C" void kernel_launch(void* const* d_in, const int* in_sizes, int n_in,
                              void* d_out, int out_size, void* d_ws, size_t ws_size,
                              hipStream_t stream) {
    const float* x   = (const float*)d_in[0];
    const int*   src = (const int*)d_in[1];
    const int*   dst = (const int*)d_in[2];
    const float* W1  = (const float*)d_in[3];
    const float* al1 = (const float*)d_in[4];
    const float* ar1 = (const float*)d_in[5];
    const float* b1  = (const float*)d_in[6];
    const float* W2  = (const float*)d_in[7];
    const float* al2 = (const float*)d_in[8];
    const float* ar2 = (const float*)d_in[9];
    const float* b2  = (const float*)d_in[10];
    const float* Wc  = (const float*)d_in[11];
    const float* bc  = (const float*)d_in[12];

    int N = in_sizes[0] / 128;
    int E = in_sizes[1];
    int NB = (N + (1 << BINB) - 1) >> BINB;

    size_t off = 0;
    auto alloc = [&](size_t bytes) -> void* {
        void* p = (char*)d_ws + off;
        off += (bytes + 255) & ~size_t(255);
        return p;
    };
    int*   bin_cnt    = (int*)alloc(sizeof(int) * NB);
    int*   binStart   = (int*)alloc(sizeof(int) * (NB + 1));
    int*   bin_cursor = (int*)alloc(sizeof(int) * NB);
    int*   rowstart   = (int*)alloc(sizeof(int) * (N + 1));
    unsigned int* coarse = (unsigned int*)alloc(sizeof(unsigned int) * E);
    ushort* bucket  = (ushort*)alloc(sizeof(ushort) * E);
    ushort* dst16   = (ushort*)alloc(sizeof(ushort) * E);
    float* wbuf     = (float*)alloc(sizeof(float) * (size_t)E * 8);
    ushort* feat    = (ushort*)alloc(sizeof(ushort) * (size_t)N * 128);
    float* el       = (float*)alloc(sizeof(float) * N * 8);
    float* er       = (float*)alloc(sizeof(float) * N * 8);
    ushort* h1      = (ushort*)alloc(sizeof(ushort) * (size_t)N * 128);
    ushort* h2      = (ushort*)alloc(sizeof(ushort) * (size_t)N * 128);
    float* meanbuf  = (float*)alloc(sizeof(float) * 128);
    ushort* Wt1     = (ushort*)alloc(sizeof(ushort) * 128 * 128);
    ushort* Wt2     = (ushort*)alloc(sizeof(ushort) * 128 * 128);

    hipMemsetAsync(bin_cnt, 0, sizeof(int) * NB, stream);
    hipMemsetAsync(meanbuf, 0, sizeof(float) * 128, stream);

    int GB = ceil_div(E, TILE);

    bin_count<<<GB, 256, 0, stream>>>(dst, bin_cnt, E, NB);
    bin_scan<<<1, 256, 0, stream>>>(bin_cnt, binStart, bin_cursor, rowstart, NB, N, E);
    bin_scatter<<<GB, 256, 0, stream>>>(src, dst, bin_cursor, coarse, E);
    fine_csr<<<NB, 256, 0, stream>>>(coarse, binStart, rowstart, bucket, dst16, N);
    convert_w<<<128, 256, 0, stream>>>(W1, W2, Wt1, Wt2);

    // layer 1 (f32 input)
    gemm_attn_mfma<false><<<ceil_div(N, 64), 256, 0, stream>>>(x, Wt1, al1, ar1, feat, el, er, N);
    edge_weights<<<2048, 256, 0, stream>>>(bucket, dst16, el, er, wbuf, E);
    aggregate<<<ceil_div(N * 64, 256), 256, 0, stream>>>(feat, wbuf, rowstart, bucket, b1, h1, N, 1);
    // layer 2 (flat bf16 input)
    gemm_attn_mfma<true><<<ceil_div(N, 64), 256, 0, stream>>>(h1, Wt2, al2, ar2, feat, el, er, N);
    edge_weights<<<2048, 256, 0, stream>>>(bucket, dst16, el, er, wbuf, E);
    aggregate<<<ceil_div(N * 64, 256), 256, 0, stream>>>(feat, wbuf, rowstart, bucket, b2, h2, N, 0);
    // readout
    mean_reduce<<<256, 256, 0, stream>>>(h2, meanbuf, N);
    classifier<<<1, 64, 0, stream>>>(meanbuf, Wc, bc, (float*)d_out, 1.0f / (float)N);
}